// Round 10
// baseline (1416.272 us; speedup 1.0000x reference)
//
#include <hip/hip_runtime.h>
#include <hip/hip_bf16.h>
#include <math.h>

#define NN 10000
#define NE 60000
#define DD 128
#define NL 15
#define LN_EPS 1e-5f

typedef __attribute__((ext_vector_type(8))) short short8;       // 8 bf16 (MFMA A/B frag)
typedef __attribute__((ext_vector_type(4))) float floatx4;      // MFMA C/D frag

__device__ __forceinline__ unsigned short f2bf(float f) {
    unsigned u = __float_as_uint(f);
    u += 0x7fff + ((u >> 16) & 1);   // RNE
    return (unsigned short)(u >> 16);
}
// packed f32x2 -> bf16x2 (v_cvt_pk_bf16_f32 on gfx950), result as one uint
__device__ __forceinline__ unsigned bc2(float a, float b) {
    __hip_bfloat162 t = __float22bfloat162_rn(make_float2(a, b));
    return *(unsigned*)&t;
}
// bf16x2 word -> two floats
__device__ __forceinline__ float bfl(unsigned w) { return __uint_as_float(w << 16); }
__device__ __forceinline__ float bfh(unsigned w) { return __uint_as_float(w & 0xffff0000u); }
// gelu(y) ~= y * sigmoid(1.5957691*y + 0.0713548*y^3)
__device__ __forceinline__ float gelu_fast(float y) {
    float u = y * y;
    float s2 = y * fmaf(u, 0.07135481283f, 1.59576912161f);
    return y * __builtin_amdgcn_rcpf(1.0f + __expf(-s2));
}

// ---- pack fp32 weights [L][K][N] -> bf16 MFMA B-fragment layout ----
// dst (within layer) = (t*S + s)*512 + l*8 + j ; virtual k = 32s+8(l>>4)+j ; n=16t+(l&15)
// PERM (stage-2 weights, K=256): physical k = ((kv&15)<<4)|(kv>>4)
__device__ __forceinline__ void pack_one(const float* __restrict__ W, unsigned short* __restrict__ P,
                                         int u, int Kk, int Nk, bool perm) {
    int per_layer = Kk * Nk;
    int i = u / per_layer;
    int v0 = u - i * per_layer;
    int S = Kk >> 5;
    int t = v0 / (S * 512);
    int rem = v0 - t * (S * 512);
    int s = rem >> 9;
    int v = rem & 511;
    int l = v >> 3, j = v & 7;
    int kv = (s << 5) + ((l >> 4) << 3) + j;
    int k = perm ? (((kv & 15) << 4) | (kv >> 4)) : kv;
    int n = (t << 4) + (l & 15);
    P[u] = f2bf(W[((size_t)i * Kk + k) * Nk + n]);
}

#define N_EW1 (NL * 384 * 256)
#define N_EW2 (NL * 256 * 128)
#define N_NW1 (NL * 256 * 256)
#define N_NW2 (NL * 256 * 128)

__global__ void pack_all(const float* __restrict__ ew1, const float* __restrict__ ew2,
                         const float* __restrict__ nw1, const float* __restrict__ nw2,
                         unsigned short* __restrict__ P) {
    int tid = blockIdx.x * blockDim.x + threadIdx.x;
    if (tid < N_EW1) { pack_one(ew1, P, tid, 384, 256, false); return; }
    tid -= N_EW1;
    if (tid < N_EW2) { pack_one(ew2, P + N_EW1, tid, 256, 128, true); return; }
    tid -= N_EW2;
    if (tid < N_NW1) { pack_one(nw1, P + N_EW1 + N_EW2, tid, 256, 256, false); return; }
    tid -= N_NW1;
    if (tid < N_NW2) { pack_one(nw2, P + N_EW1 + N_EW2 + N_NW1, tid, 256, 128, true); return; }
}

// ---- CSR build (once per launch) ----
__global__ void hist_kernel(const int* __restrict__ ecol, int* __restrict__ cnt) {
    int e = blockIdx.x * blockDim.x + threadIdx.x;
    if (e < NE) atomicAdd(&cnt[ecol[e]], 1);
}

__global__ void scan_kernel(const int* __restrict__ cnt, int* __restrict__ starts,
                            int* __restrict__ cursor, float* __restrict__ cinv) {
    __shared__ int part[256];
    int t = threadIdx.x;
    const int chunk = (NN + 255) / 256;
    int lo = t * chunk;
    int hi = lo + chunk; if (hi > NN) hi = NN;
    int s = 0;
    for (int n = lo; n < hi; ++n) s += cnt[n];
    part[t] = s;
    __syncthreads();
    for (int off = 1; off < 256; off <<= 1) {
        int v = (t >= off) ? part[t - off] : 0;
        __syncthreads();
        part[t] += v;
        __syncthreads();
    }
    int base = part[t] - s;
    for (int n = lo; n < hi; ++n) {
        int c = cnt[n];
        starts[n] = base; cursor[n] = base;
        cinv[n] = 1.0f / (float)(c > 0 ? c : 1);
        base += c;
    }
}

// fills eidx (slot -> original edge) and CSR-sorted endpoint arrays
__global__ void fill_kernel(const int* __restrict__ erow, const int* __restrict__ ecol,
                            int* __restrict__ cursor, int* __restrict__ eidx,
                            int* __restrict__ erow_s, int* __restrict__ ecol_s) {
    int e = blockIdx.x * blockDim.x + threadIdx.x;
    if (e < NE) {
        int c = ecol[e];
        int slot = atomicAdd(&cursor[c], 1);
        eidx[slot] = e;
        erow_s[slot] = erow[e];
        ecol_s[slot] = c;
    }
}

// ---- one-time fp32 -> bf16 conversion: x shadow + CSR-ordered edge state ----
__global__ void init_shadow(const float* __restrict__ x, const float* __restrict__ ea,
                            const int* __restrict__ eidx,
                            unsigned short* __restrict__ xb, unsigned short* __restrict__ eb) {
    int t = blockIdx.x * blockDim.x + threadIdx.x;
    const int NX = NN * DD / 4;
    const int NEA = NE * DD / 4;
    if (t < NX) {
        float4 v = *(const float4*)&x[(size_t)t * 4];
        uint2 p; p.x = bc2(v.x, v.y); p.y = bc2(v.z, v.w);
        *(uint2*)&xb[(size_t)t * 4] = p;
    } else if (t < NX + NEA) {
        size_t u = (size_t)(t - NX);
        int slot = (int)(u >> 5);          // DD/4 = 32 float4-chunks per row
        int j = (int)(u & 31);
        int e = eidx[slot];
        float4 v = *(const float4*)&ea[(size_t)e * DD + j * 4];
        uint2 p; p.x = bc2(v.x, v.y); p.y = bc2(v.z, v.w);
        *(uint2*)&eb[u * 4] = p;
    }
}

// ============================================================================
// EDGE kernel: ROWS=64, 8 waves (512 thr). Wave w owns stage-1 n-tiles {2w,2w+1}
// and stage-2 n-tile {w}, across ALL 4 m-tiles (acc[4][2] = 32 VGPR). Weights are
// read from L2 exactly ONCE per 64 rows (vs once per 32 in r9) — halves the
// dominant 488MB/dispatch L2 weight stream. H' physical layout is IDENTICAL to
// the r9 mapping (slot algebra 4((t>>2)&1)+(t&3), gg-term t>>3 — re-derived), so
// W2p's k-permutation and stage-2 reads are unchanged.
// r8 lesson (ROWS=64, MT=4 x 4-ntl): VGPR 100 + LDS 53KB -> occupancy 18%,
// regression. Here acc stays 32 regs; LDS 57KB -> 2 blocks x 8 waves = 16 w/CU.
// ============================================================================
__global__ __launch_bounds__(512, 4)
void mlp_edge64(const unsigned short* __restrict__ xb16,
                const int* __restrict__ erow, const int* __restrict__ ecol,   // CSR-sorted
                const unsigned short* __restrict__ eas16,   // bf16 edge state (slot order)
                const int* __restrict__ eidx,               // slot -> orig edge (final layer)
                float* __restrict__ target,                 // final-layer f32 out or null
                unsigned short* __restrict__ shadow,        // eas16
                const unsigned short* __restrict__ W1p, const unsigned short* __restrict__ W2p,
                const float* __restrict__ b1, const float* __restrict__ g1, const float* __restrict__ bt1,
                const float* __restrict__ b2, const float* __restrict__ g2, const float* __restrict__ bt2)
{
    constexpr int K1 = 384, S1 = 12, ROWS = 64;
    __shared__ union {
        unsigned short a1[ROWS * K1];     // 48KB gather tile (XOR-swizzled groups of 8)
        unsigned short h[ROWS * 256];     // 32KB stage-1 activations (r9-identical layout)
    } sm;
    __shared__ float red1[ROWS][16];
    __shared__ float red2[ROWS][16];

    const int tid  = threadIdx.x;
    const int lane = tid & 63;
    const int w    = tid >> 6;        // 0..7
    const int q    = lane >> 4;
    const int c15  = lane & 15;
    const int r0   = blockIdx.x * ROWS;

    // ---------------- gather -> a1: thread owns row r=tid>>3, col-group g=tid&7 ----------------
    {
        const int r = tid >> 3;
        const int g = tid & 7;
        const int row_g = r0 + r;
        const int rg = (row_g < NE) ? row_g : 0;     // NE % 64 != 0 -> clamp
        const unsigned short* baseA = &xb16[(size_t)erow[rg] * DD];
        const unsigned short* baseB = &xb16[(size_t)ecol[rg] * DD];
        const unsigned short* baseC = &eas16[(size_t)rg * DD];
        #pragma unroll
        for (int it = 0; it < 6; ++it) {
            const int gg = g + 8 * it;
            const int p = gg << 3;                  // region uniform per it
            const unsigned short* src = (p < 128) ? (baseA + p)
                                      : (p < 256) ? (baseB + (p - 128))
                                                  : (baseC + (p - 256));
            uint4 v = *(const uint4*)src;
            *(uint4*)&sm.a1[r * K1 + ((gg ^ (r & 7)) << 3)] = v;
        }
    }
    __syncthreads();

    // hoisted stage-2 bias/gain loads (1 col per lane): hide under stage-1 MFMA
    const int col2 = (w << 4) + c15;
    float b2c = b2[col2], g2c = g2[col2], t2c = bt2[col2];

    // ---------------- stage 1 MFMA: n-tiles {2w,2w+1} x m-tiles 0..3 ----------------
    floatx4 acc[4][2];
    #pragma unroll
    for (int mt = 0; mt < 4; ++mt)
        #pragma unroll
        for (int jn = 0; jn < 2; ++jn)
            acc[mt][jn] = (floatx4){0.f, 0.f, 0.f, 0.f};

    __builtin_amdgcn_s_setprio(1);
    #pragma unroll
    for (int s = 0; s < S1; ++s) {
        short8 af[4];
        #pragma unroll
        for (int mt = 0; mt < 4; ++mt) {
            int row  = (mt << 4) + c15;
            int kgrp = ((s << 2) + q) ^ (row & 7);
            af[mt] = *(const short8*)&sm.a1[row * K1 + (kgrp << 3)];
        }
        #pragma unroll
        for (int jn = 0; jn < 2; ++jn) {
            const short8 bf = *(const short8*)&W1p[(((((w << 1) + jn) * S1 + s) << 6) + lane) << 3];
            #pragma unroll
            for (int mt = 0; mt < 4; ++mt)
                acc[mt][jn] = __builtin_amdgcn_mfma_f32_16x16x32_bf16(af[mt], bf, acc[mt][jn], 0, 0, 0);
        }
    }
    __builtin_amdgcn_s_setprio(0);

    // residual t_old: read own-row bf16 state back from the gather tile in LDS
    // (virtual cols 256..383; a1 intact until sm.h writes after the red1 barrier)
    float tpre[4][4];
    #pragma unroll
    for (int jm = 0; jm < 4; ++jm)
        #pragma unroll
        for (int r = 0; r < 4; ++r) {
            int row = (jm << 4) + (q << 2) + r;
            int vc = 256 + col2;
            int addr = row * K1 + ((((vc >> 3) ^ (row & 7)) << 3) | (vc & 7));
            tpre[jm][r] = __uint_as_float((unsigned)sm.a1[addr] << 16);
        }

    // bias + in-register LN1 partial stats (2 cols/lane)
    float b1c[2], g1c[2], t1c[2];
    #pragma unroll
    for (int jn = 0; jn < 2; ++jn) {
        int col = (((w << 1) + jn) << 4) + c15;
        b1c[jn] = b1[col]; g1c[jn] = g1[col]; t1c[jn] = bt1[col];
    }
    #pragma unroll
    for (int mt = 0; mt < 4; ++mt)
        #pragma unroll
        for (int r = 0; r < 4; ++r) {
            float v0 = acc[mt][0][r] + b1c[0]; acc[mt][0][r] = v0;
            float v1 = acc[mt][1][r] + b1c[1]; acc[mt][1][r] = v1;
            float p = v0 + v1;
            float sq = fmaf(v0, v0, v1 * v1);
            p += __shfl_xor(p, 1);  sq += __shfl_xor(sq, 1);
            p += __shfl_xor(p, 2);  sq += __shfl_xor(sq, 2);
            p += __shfl_xor(p, 4);  sq += __shfl_xor(sq, 4);
            p += __shfl_xor(p, 8);  sq += __shfl_xor(sq, 8);
            if (c15 == 0) {
                int row = (mt << 4) + (q << 2) + r;
                red1[row][(w << 1) + 0] = p;
                red1[row][(w << 1) + 1] = sq;
            }
        }
    __syncthreads();   // red1 visible; all waves done with a1 (incl. t_old) -> h writes safe

    // ---- apply LN1 + GELU, write H' (r9-identical physical layout) ----
    const int qnp = w >> 1;    // = t>>2 for t = 2w+jn
    const int hh  = w & 1;     // = (t>>1)&1
    #pragma unroll
    for (int mt = 0; mt < 4; ++mt)
        #pragma unroll
        for (int r = 0; r < 4; ++r) {
            int row = (mt << 4) + (q << 2) + r;
            const float4 p0 = *(const float4*)&red1[row][0];
            const float4 p1 = *(const float4*)&red1[row][4];
            const float4 p2 = *(const float4*)&red1[row][8];
            const float4 p3 = *(const float4*)&red1[row][12];
            float p  = p0.x + p0.z + p1.x + p1.z + p2.x + p2.z + p3.x + p3.z;
            float sq = p0.y + p0.w + p1.y + p1.w + p2.y + p2.w + p3.y + p3.w;
            float mu = p * (1.0f / 256.0f);
            float rs = rsqrtf(sq * (1.0f / 256.0f) - mu * mu + LN_EPS);
            float y0 = gelu_fast((acc[mt][0][r] - mu) * rs * g1c[0] + t1c[0]);
            float y1 = gelu_fast((acc[mt][1][r] - mu) * rs * g1c[1] + t1c[1]);
            unsigned hp = bc2(y0, y1);
            int gg = (c15 << 1) + (qnp >> 1);
            int addr = row * 256 + (((gg ^ (row & 7)) << 3) | ((qnp & 1) << 2) | (hh << 1));
            *(unsigned*)&sm.h[addr] = hp;
        }
    __syncthreads();

    // ---------------- stage 2: n-tile w x m-tiles 0..3 ----------------
    floatx4 acc2[4];
    #pragma unroll
    for (int jm = 0; jm < 4; ++jm) acc2[jm] = (floatx4){0.f, 0.f, 0.f, 0.f};

    __builtin_amdgcn_s_setprio(1);
    #pragma unroll
    for (int s = 0; s < 8; ++s) {
        short8 a2[4];
        #pragma unroll
        for (int jm = 0; jm < 4; ++jm) {
            int mrow = (jm << 4) + c15;
            int kgrp = ((s << 2) + q) ^ (mrow & 7);
            a2[jm] = *(const short8*)&sm.h[mrow * 256 + (kgrp << 3)];
        }
        const short8 b = *(const short8*)&W2p[((((w << 3) + s) << 6) + lane) << 3];
        #pragma unroll
        for (int jm = 0; jm < 4; ++jm)
            acc2[jm] = __builtin_amdgcn_mfma_f32_16x16x32_bf16(a2[jm], b, acc2[jm], 0, 0, 0);
    }
    __builtin_amdgcn_s_setprio(0);

    #pragma unroll
    for (int jm = 0; jm < 4; ++jm)
        #pragma unroll
        for (int r = 0; r < 4; ++r) {
            float v = acc2[jm][r] + b2c;
            acc2[jm][r] = v;
            float p = v, sq = v * v;
            p += __shfl_xor(p, 1);  sq += __shfl_xor(sq, 1);
            p += __shfl_xor(p, 2);  sq += __shfl_xor(sq, 2);
            p += __shfl_xor(p, 4);  sq += __shfl_xor(sq, 4);
            p += __shfl_xor(p, 8);  sq += __shfl_xor(sq, 8);
            if (c15 == 0) {
                int row = (jm << 4) + (q << 2) + r;
                red2[row][(w << 1) + 0] = p;
                red2[row][(w << 1) + 1] = sq;
            }
        }
    __syncthreads();   // red2 visible; all stage-2 h reads done -> h region reusable

    // ---------------- epilogue: LN2 + residual; stage bf16 for coalesced store ----------------
    #pragma unroll
    for (int jm = 0; jm < 4; ++jm)
        #pragma unroll
        for (int r = 0; r < 4; ++r) {
            int row = (jm << 4) + (q << 2) + r;
            const float4 p0 = *(const float4*)&red2[row][0];
            const float4 p1 = *(const float4*)&red2[row][4];
            const float4 p2 = *(const float4*)&red2[row][8];
            const float4 p3 = *(const float4*)&red2[row][12];
            float p  = p0.x + p0.z + p1.x + p1.z + p2.x + p2.z + p3.x + p3.z;
            float sq = p0.y + p0.w + p1.y + p1.w + p2.y + p2.w + p3.y + p3.w;
            float mu = p * (1.0f / 128.0f);
            float rs = rsqrtf(sq * (1.0f / 128.0f) - mu * mu + LN_EPS);
            float o = (acc2[jm][r] - mu) * rs * g2c + t2c;
            float t = tpre[jm][r] + o;
            int oaddr = row * 128 + ((((col2 >> 3) ^ (row & 7)) << 3) | (col2 & 7));
            sm.h[oaddr] = f2bf(t);
            int rowg = r0 + row;
            if (target && rowg < NE) {               // final layer: fp32 out in ORIGINAL order
                int orig = eidx[rowg];
                target[(size_t)orig * DD + col2] = t;
            }
        }
    __syncthreads();

    // lane-consecutive coalesced bf16 store: chunk c = tid + 512k -> 16B at byte c*16
    #pragma unroll
    for (int k = 0; k < 2; ++k) {
        int c = tid + (k << 9);
        int row = c >> 4;
        int G = c & 15;
        if (r0 + row < NE) {
            uint4 v = *(const uint4*)&sm.h[row * 128 + ((G ^ (row & 7)) << 3)];
            *(uint4*)&shadow[(size_t)(r0 + row) * DD + (G << 3)] = v;
        }
    }
}

// ---- NODE kernel (r9 path, unchanged): ROWS=32, 4 waves ----
template <int K1, int ROWS_TOTAL>
__global__ __launch_bounds__(256, 4)
void mlp_node(const unsigned short* __restrict__ xb16,
              const unsigned short* __restrict__ eas16,   // bf16 edge state (slot order)
              const int* __restrict__ starts, const int* __restrict__ cnt,
              const float* __restrict__ cinv,
              float* __restrict__ target,                 // fp32 x state
              unsigned short* __restrict__ shadow,        // xb16
              const unsigned short* __restrict__ W1p, const unsigned short* __restrict__ W2p,
              const float* __restrict__ b1, const float* __restrict__ g1, const float* __restrict__ bt1,
              const float* __restrict__ b2, const float* __restrict__ g2, const float* __restrict__ bt2)
{
    constexpr int S1 = K1 / 32;
    constexpr int ROWS = 32;
    __shared__ union {
        unsigned short a1[ROWS * K1];
        unsigned short h[ROWS * 256];
    } sm;
    __shared__ float red1[ROWS][8];
    __shared__ float red2[ROWS][8];

    const int tid  = threadIdx.x;
    const int lane = tid & 63;
    const int w    = tid >> 6;
    const int q    = lane >> 4;
    const int c15  = lane & 15;
    const int r0   = blockIdx.x * ROWS;

    const int qn = w & 3;
    const int np = w & 3;

    {
        const int r = tid >> 3;
        const int g = tid & 7;
        const int row_g = r0 + r;
        const bool ok = (ROWS_TOTAL % ROWS == 0) || (row_g < ROWS_TOTAL);
        const int rg = ok ? row_g : 0;
        const unsigned short* baseA = &xb16[(size_t)rg * DD];
        #pragma unroll
        for (int it = 0; it < 2; ++it) {
            const int gg = g + 8 * it;
            uint4 v = *(const uint4*)(baseA + (gg << 3));
            *(uint4*)&sm.a1[r * K1 + ((gg ^ (r & 7)) << 3)] = v;
        }
        // fused CSR mean over CONTIGUOUS bf16 edge-state span
        const int st = starts[rg];
        const int de = cnt[rg];
        const float ci = cinv[rg];
        float4 sa0 = {0.f,0.f,0.f,0.f}, sa1 = sa0, sb0 = sa0, sb1 = sa0;
        const unsigned short* er = &eas16[(size_t)st * DD + (g << 3)];
        for (int i = 0; i < de; ++i, er += DD) {
            uint4 a = *(const uint4*)er;
            uint4 b = *(const uint4*)(er + 64);
            sa0.x += bfl(a.x); sa0.y += bfh(a.x); sa0.z += bfl(a.y); sa0.w += bfh(a.y);
            sa1.x += bfl(a.z); sa1.y += bfh(a.z); sa1.z += bfl(a.w); sa1.w += bfh(a.w);
            sb0.x += bfl(b.x); sb0.y += bfh(b.x); sb0.z += bfl(b.y); sb0.w += bfh(b.y);
            sb1.x += bfl(b.z); sb1.y += bfh(b.z); sb1.z += bfl(b.w); sb1.w += bfh(b.w);
        }
        uint4 v;
        v.x = bc2(sa0.x * ci, sa0.y * ci); v.y = bc2(sa0.z * ci, sa0.w * ci);
        v.z = bc2(sa1.x * ci, sa1.y * ci); v.w = bc2(sa1.z * ci, sa1.w * ci);
        const int gg2 = g + 16;
        *(uint4*)&sm.a1[r * K1 + ((gg2 ^ (r & 7)) << 3)] = v;
        v.x = bc2(sb0.x * ci, sb0.y * ci); v.y = bc2(sb0.z * ci, sb0.w * ci);
        v.z = bc2(sb1.x * ci, sb1.y * ci); v.w = bc2(sb1.z * ci, sb1.w * ci);
        const int gg3 = g + 24;
        *(uint4*)&sm.a1[r * K1 + ((gg3 ^ (r & 7)) << 3)] = v;
    }
    __syncthreads();

    float b2c[2], g2c[2], t2c[2];
    #pragma unroll
    for (int jn = 0; jn < 2; ++jn) {
        int col = (((np << 1) + jn) << 4) + c15;
        b2c[jn] = b2[col]; g2c[jn] = g2[col]; t2c[jn] = bt2[col];
    }

    floatx4 acc[2][4];
    #pragma unroll
    for (int mt = 0; mt < 2; ++mt)
        #pragma unroll
        for (int ntl = 0; ntl < 4; ++ntl)
            acc[mt][ntl] = (floatx4){0.f, 0.f, 0.f, 0.f};

    __builtin_amdgcn_s_setprio(1);
    #pragma unroll
    for (int s = 0; s < S1; ++s) {
        short8 af[2];
        #pragma unroll
        for (int mt = 0; mt < 2; ++mt) {
            int row  = (mt << 4) + c15;
            int kgrp = ((s << 2) + q) ^ (row & 7);
            af[mt] = *(const short8*)&sm.a1[row * K1 + (kgrp << 3)];
        }
        #pragma unroll
        for (int ntl = 0; ntl < 4; ++ntl) {
            const short8 bf = *(const short8*)&W1p[((((((qn << 2) + ntl) * S1) + s) << 6) + lane) << 3];
            #pragma unroll
            for (int mt = 0; mt < 2; ++mt)
                acc[mt][ntl] = __builtin_amdgcn_mfma_f32_16x16x32_bf16(af[mt], bf, acc[mt][ntl], 0, 0, 0);
        }
    }
    __builtin_amdgcn_s_setprio(0);

    float b1c[4], g1c[4], t1c[4];
    #pragma unroll
    for (int ntl = 0; ntl < 4; ++ntl) {
        int col = (((qn << 2) + ntl) << 4) + c15;
        b1c[ntl] = b1[col]; g1c[ntl] = g1[col]; t1c[ntl] = bt1[col];
    }
    #pragma unroll
    for (int mt = 0; mt < 2; ++mt)
        #pragma unroll
        for (int r = 0; r < 4; ++r) {
            float p = 0.f, sq = 0.f;
            #pragma unroll
            for (int ntl = 0; ntl < 4; ++ntl) {
                float v = acc[mt][ntl][r] + b1c[ntl];
                acc[mt][ntl][r] = v;
                p += v; sq += v * v;
            }
            p += __shfl_xor(p, 1);  sq += __shfl_xor(sq, 1);
            p += __shfl_xor(p, 2);  sq += __shfl_xor(sq, 2);
            p += __shfl_xor(p, 4);  sq += __shfl_xor(sq, 4);
            p += __shfl_xor(p, 8);  sq += __shfl_xor(sq, 8);
            if (c15 == 0) {
                int row = (mt << 4) + (q << 2) + r;
                red1[row][(qn << 1) + 0] = p;
                red1[row][(qn << 1) + 1] = sq;
            }
        }
    __syncthreads();

    #pragma unroll
    for (int mt = 0; mt < 2; ++mt)
        #pragma unroll
        for (int r = 0; r < 4; ++r) {
            int row = (mt << 4) + (q << 2) + r;
            const float4 p0 = *(const float4*)&red1[row][0];
            const float4 p1 = *(const float4*)&red1[row][4];
            float p  = p0.x + p0.z + p1.x + p1.z;
            float sq = p0.y + p0.w + p1.y + p1.w;
            float mu = p * (1.0f / 256.0f);
            float rs = rsqrtf(sq * (1.0f / 256.0f) - mu * mu + LN_EPS);
            float y0 = gelu_fast((acc[mt][0][r] - mu) * rs * g1c[0] + t1c[0]);
            float y1 = gelu_fast((acc[mt][1][r] - mu) * rs * g1c[1] + t1c[1]);
            float y2 = gelu_fast((acc[mt][2][r] - mu) * rs * g1c[2] + t1c[2]);
            float y3 = gelu_fast((acc[mt][3][r] - mu) * rs * g1c[3] + t1c[3]);
            uint2 hp;
            hp.x = bc2(y0, y1);
            hp.y = bc2(y2, y3);
            int gg = (c15 << 1) + (qn >> 1);
            int addr = row * 256 + (((gg ^ (row & 7)) << 3) | ((qn & 1) << 2));
            *(uint2*)&sm.h[addr] = hp;
        }
    __syncthreads();

    floatx4 acc2[2][2];
    #pragma unroll
    for (int jm = 0; jm < 2; ++jm)
        #pragma unroll
        for (int jn = 0; jn < 2; ++jn)
            acc2[jm][jn] = (floatx4){0.f, 0.f, 0.f, 0.f};

    __builtin_amdgcn_s_setprio(1);
    #pragma unroll
    for (int s = 0; s < 8; ++s) {
        short8 a2[2];
        #pragma unroll
        for (int jm = 0; jm < 2; ++jm) {
            int mrow = (jm << 4) + c15;
            int kgrp = ((s << 2) + q) ^ (mrow & 7);
            a2[jm] = *(const short8*)&sm.h[mrow * 256 + (kgrp << 3)];
        }
        #pragma unroll
        for (int jn = 0; jn < 2; ++jn) {
            int nt = (np << 1) + jn;
            const short8 b = *(const short8*)&W2p[((((nt << 3) + s) << 6) + lane) << 3];
            #pragma unroll
            for (int jm = 0; jm < 2; ++jm)
                acc2[jm][jn] = __builtin_amdgcn_mfma_f32_16x16x32_bf16(a2[jm], b, acc2[jm][jn], 0, 0, 0);
        }
    }
    __builtin_amdgcn_s_setprio(0);

    float tpre[2][4][2];
    #pragma unroll
    for (int jm = 0; jm < 2; ++jm)
        #pragma unroll
        for (int r = 0; r < 4; ++r) {
            int row = (jm << 4) + (q << 2) + r;
            int rowg = r0 + row;
            const bool okk = (ROWS_TOTAL % ROWS == 0) || (rowg < ROWS_TOTAL);
            const int rgs = okk ? rowg : 0;
            #pragma unroll
            for (int jn = 0; jn < 2; ++jn) {
                int col = (((np << 1) + jn) << 4) + c15;
                tpre[jm][r][jn] = target[(size_t)rgs * DD + col];
            }
        }

    #pragma unroll
    for (int jm = 0; jm < 2; ++jm)
        #pragma unroll
        for (int r = 0; r < 4; ++r) {
            float p = 0.f, sq = 0.f;
            #pragma unroll
            for (int jn = 0; jn < 2; ++jn) {
                float v = acc2[jm][jn][r] + b2c[jn];
                acc2[jm][jn][r] = v;
                p += v; sq += v * v;
            }
            p += __shfl_xor(p, 1);  sq += __shfl_xor(sq, 1);
            p += __shfl_xor(p, 2);  sq += __shfl_xor(sq, 2);
            p += __shfl_xor(p, 4);  sq += __shfl_xor(sq, 4);
            p += __shfl_xor(p, 8);  sq += __shfl_xor(sq, 8);
            if (c15 == 0) {
                int row = (jm << 4) + (q << 2) + r;
                red2[row][(np << 1) + 0] = p;
                red2[row][(np << 1) + 1] = sq;
            }
        }
    __syncthreads();

    #pragma unroll
    for (int jm = 0; jm < 2; ++jm)
        #pragma unroll
        for (int r = 0; r < 4; ++r) {
            int row = (jm << 4) + (q << 2) + r;
            const float4 pp0 = *(const float4*)&red2[row][0];
            const float4 pp1 = *(const float4*)&red2[row][4];
            float p  = pp0.x + pp0.z + pp1.x + pp1.z;
            float sq = pp0.y + pp0.w + pp1.y + pp1.w;
            float mu = p * (1.0f / 128.0f);
            float rs = rsqrtf(sq * (1.0f / 128.0f) - mu * mu + LN_EPS);
            int rowg = r0 + row;
            const bool okk = (ROWS_TOTAL % ROWS == 0) || (rowg < ROWS_TOTAL);
            #pragma unroll
            for (int jn = 0; jn < 2; ++jn) {
                int col = (((np << 1) + jn) << 4) + c15;
                float o = (acc2[jm][jn][r] - mu) * rs * g2c[jn] + t2c[jn];
                float t = tpre[jm][r][jn] + o;
                if (okk) {
                    target[(size_t)rowg * DD + col] = t;
                    shadow[(size_t)rowg * DD + col] = f2bf(t);
                }
            }
        }
}

extern "C" void kernel_launch(void* const* d_in, const int* in_sizes, int n_in,
                              void* d_out, int out_size, void* d_ws, size_t ws_size,
                              hipStream_t stream) {
    const float* x_in  = (const float*)d_in[0];
    const int*   ei    = (const int*)  d_in[1];
    const float* ea_in = (const float*)d_in[2];
    const float* ew1 = (const float*)d_in[3];
    const float* eb1 = (const float*)d_in[4];
    const float* eg1 = (const float*)d_in[5];
    const float* ebt1= (const float*)d_in[6];
    const float* ew2 = (const float*)d_in[7];
    const float* eb2 = (const float*)d_in[8];
    const float* eg2 = (const float*)d_in[9];
    const float* ebt2= (const float*)d_in[10];
    const float* nw1 = (const float*)d_in[11];
    const float* nb1 = (const float*)d_in[12];
    const float* ng1 = (const float*)d_in[13];
    const float* nbt1= (const float*)d_in[14];
    const float* nw2 = (const float*)d_in[15];
    const float* nb2 = (const float*)d_in[16];
    const float* ng2 = (const float*)d_in[17];
    const float* nbt2= (const float*)d_in[18];

    const int* erow = ei;
    const int* ecol = ei + NE;

    float* xbuf  = (float*)d_out;            // [NN, DD] fp32 x residual state (output 0)
    float* eabuf = (float*)d_out + NN * DD;  // [NE, DD] fp32 edge output (written on last layer)

    // workspace layout
    unsigned short* ew1p  = (unsigned short*)d_ws;
    unsigned short* ew2p  = ew1p + N_EW1;
    unsigned short* nw1p  = ew2p + N_EW2;
    unsigned short* nw2p  = nw1p + N_NW1;
    unsigned short* xb16  = nw2p + N_NW2;            // [NN, DD] bf16 shadow of x
    unsigned short* eas16 = xb16 + (size_t)NN * DD;  // [NE, DD] bf16 edge STATE (CSR slot order)
    int*   cnt    = (int*)(eas16 + (size_t)NE * DD);
    int*   starts = cnt + NN;
    int*   cursor = starts + NN;
    int*   eidx   = cursor + NN;                     // slot -> original edge
    int*   erow_s = eidx + NE;                       // CSR-sorted endpoints
    int*   ecol_s = erow_s + NE;
    float* cinv   = (float*)(ecol_s + NE);

    hipMemcpyAsync(xbuf, x_in, (size_t)NN * DD * sizeof(float), hipMemcpyDeviceToDevice, stream);

    // CSR build (+ sorted endpoint arrays)
    hipMemsetAsync(cnt, 0, NN * sizeof(int), stream);
    hist_kernel<<<(NE + 255) / 256, 256, 0, stream>>>(ecol, cnt);
    scan_kernel<<<1, 256, 0, stream>>>(cnt, starts, cursor, cinv);
    fill_kernel<<<(NE + 255) / 256, 256, 0, stream>>>(erow, ecol, cursor, eidx, erow_s, ecol_s);

    // bf16 x shadow + CSR-ordered bf16 edge state (needs eidx -> after fill)
    {
        int ntot = (NN * DD + NE * DD) / 4;
        init_shadow<<<(ntot + 255) / 256, 256, 0, stream>>>(x_in, ea_in, eidx, xb16, eas16);
    }

    // weight packing (stage-2 weights get the k-permutation)
    {
        int ntot = N_EW1 + N_EW2 + N_NW1 + N_NW2;
        pack_all<<<(ntot + 255) / 256, 256, 0, stream>>>(ew1, ew2, nw1, nw2, ew1p);
    }

    for (int i = 0; i < NL; ++i) {
        mlp_edge64<<<(NE + 63) / 64, 512, 0, stream>>>(
            xb16, erow_s, ecol_s, eas16, eidx,
            (i == NL - 1) ? eabuf : nullptr, eas16,
            ew1p + (size_t)i * 384 * 256, ew2p + (size_t)i * 256 * 128,
            eb1 + (size_t)i * 256, eg1 + (size_t)i * 256, ebt1 + (size_t)i * 256,
            eb2 + (size_t)i * 128, eg2 + (size_t)i * 128, ebt2 + (size_t)i * 128);
        mlp_node<256, NN><<<(NN + 31) / 32, 256, 0, stream>>>(
            xb16, eas16, starts, cnt, cinv,
            xbuf, xb16,
            nw1p + (size_t)i * 256 * 256, nw2p + (size_t)i * 256 * 128,
            nb1 + (size_t)i * 256, ng1 + (size_t)i * 256, nbt1 + (size_t)i * 256,
            nb2 + (size_t)i * 128, ng2 + (size_t)i * 128, nbt2 + (size_t)i * 128);
    }
}

// Round 11
// 1089.460 us; speedup vs baseline: 1.3000x; 1.3000x over previous
//
#include <hip/hip_runtime.h>
#include <hip/hip_bf16.h>
#include <math.h>

#define NN 10000
#define NE 60000
#define DD 128
#define NL 15
#define LN_EPS 1e-5f

typedef __attribute__((ext_vector_type(8))) short short8;       // 8 bf16 (MFMA A/B frag)
typedef __attribute__((ext_vector_type(4))) float floatx4;      // MFMA C/D frag

__device__ __forceinline__ unsigned short f2bf(float f) {
    unsigned u = __float_as_uint(f);
    u += 0x7fff + ((u >> 16) & 1);   // RNE
    return (unsigned short)(u >> 16);
}
// packed f32x2 -> bf16x2 (v_cvt_pk_bf16_f32 on gfx950), result as one uint
__device__ __forceinline__ unsigned bc2(float a, float b) {
    __hip_bfloat162 t = __float22bfloat162_rn(make_float2(a, b));
    return *(unsigned*)&t;
}
// bf16x2 word -> two floats
__device__ __forceinline__ float bfl(unsigned w) { return __uint_as_float(w << 16); }
__device__ __forceinline__ float bfh(unsigned w) { return __uint_as_float(w & 0xffff0000u); }
// gelu(y) ~= y * sigmoid(1.5957691*y + 0.0713548*y^3)
__device__ __forceinline__ float gelu_fast(float y) {
    float u = y * y;
    float s2 = y * fmaf(u, 0.07135481283f, 1.59576912161f);
    return y * __builtin_amdgcn_rcpf(1.0f + __expf(-s2));
}

// ---- pack fp32 weights [L][K][N] -> bf16 MFMA B-fragment layout ----
// dst (within layer) = (t*S + s)*512 + l*8 + j ; virtual k = 32s+8(l>>4)+j ; n=16t+(l&15)
// PERM (stage-2 weights, K=256): physical k = ((kv&15)<<4)|(kv>>4)
__device__ __forceinline__ void pack_one(const float* __restrict__ W, unsigned short* __restrict__ P,
                                         int u, int Kk, int Nk, bool perm) {
    int per_layer = Kk * Nk;
    int i = u / per_layer;
    int v0 = u - i * per_layer;
    int S = Kk >> 5;
    int t = v0 / (S * 512);
    int rem = v0 - t * (S * 512);
    int s = rem >> 9;
    int v = rem & 511;
    int l = v >> 3, j = v & 7;
    int kv = (s << 5) + ((l >> 4) << 3) + j;
    int k = perm ? (((kv & 15) << 4) | (kv >> 4)) : kv;
    int n = (t << 4) + (l & 15);
    P[u] = f2bf(W[((size_t)i * Kk + k) * Nk + n]);
}

#define N_EW1 (NL * 384 * 256)
#define N_EW2 (NL * 256 * 128)
#define N_NW1 (NL * 256 * 256)
#define N_NW2 (NL * 256 * 128)

__global__ void pack_all(const float* __restrict__ ew1, const float* __restrict__ ew2,
                         const float* __restrict__ nw1, const float* __restrict__ nw2,
                         unsigned short* __restrict__ P) {
    int tid = blockIdx.x * blockDim.x + threadIdx.x;
    if (tid < N_EW1) { pack_one(ew1, P, tid, 384, 256, false); return; }
    tid -= N_EW1;
    if (tid < N_EW2) { pack_one(ew2, P + N_EW1, tid, 256, 128, true); return; }
    tid -= N_EW2;
    if (tid < N_NW1) { pack_one(nw1, P + N_EW1 + N_EW2, tid, 256, 256, false); return; }
    tid -= N_NW1;
    if (tid < N_NW2) { pack_one(nw2, P + N_EW1 + N_EW2 + N_NW1, tid, 256, 128, true); return; }
}

// ---- CSR build (once per launch) ----
__global__ void hist_kernel(const int* __restrict__ ecol, int* __restrict__ cnt) {
    int e = blockIdx.x * blockDim.x + threadIdx.x;
    if (e < NE) atomicAdd(&cnt[ecol[e]], 1);
}

__global__ void scan_kernel(const int* __restrict__ cnt, int* __restrict__ starts,
                            int* __restrict__ cursor, float* __restrict__ cinv) {
    __shared__ int part[256];
    int t = threadIdx.x;
    const int chunk = (NN + 255) / 256;
    int lo = t * chunk;
    int hi = lo + chunk; if (hi > NN) hi = NN;
    int s = 0;
    for (int n = lo; n < hi; ++n) s += cnt[n];
    part[t] = s;
    __syncthreads();
    for (int off = 1; off < 256; off <<= 1) {
        int v = (t >= off) ? part[t - off] : 0;
        __syncthreads();
        part[t] += v;
        __syncthreads();
    }
    int base = part[t] - s;
    for (int n = lo; n < hi; ++n) {
        int c = cnt[n];
        starts[n] = base; cursor[n] = base;
        cinv[n] = 1.0f / (float)(c > 0 ? c : 1);
        base += c;
    }
}

// fills eidx (slot -> original edge) and CSR-sorted endpoint arrays
__global__ void fill_kernel(const int* __restrict__ erow, const int* __restrict__ ecol,
                            int* __restrict__ cursor, int* __restrict__ eidx,
                            int* __restrict__ erow_s, int* __restrict__ ecol_s) {
    int e = blockIdx.x * blockDim.x + threadIdx.x;
    if (e < NE) {
        int c = ecol[e];
        int slot = atomicAdd(&cursor[c], 1);
        eidx[slot] = e;
        erow_s[slot] = erow[e];
        ecol_s[slot] = c;
    }
}

// ---- one-time fp32 -> bf16 conversion: x shadow + CSR-ordered edge state ----
__global__ void init_shadow(const float* __restrict__ x, const float* __restrict__ ea,
                            const int* __restrict__ eidx,
                            unsigned short* __restrict__ xb, unsigned short* __restrict__ eb) {
    int t = blockIdx.x * blockDim.x + threadIdx.x;
    const int NX = NN * DD / 4;
    const int NEA = NE * DD / 4;
    if (t < NX) {
        float4 v = *(const float4*)&x[(size_t)t * 4];
        uint2 p; p.x = bc2(v.x, v.y); p.y = bc2(v.z, v.w);
        *(uint2*)&xb[(size_t)t * 4] = p;
    } else if (t < NX + NEA) {
        size_t u = (size_t)(t - NX);
        int slot = (int)(u >> 5);          // DD/4 = 32 float4-chunks per row
        int j = (int)(u & 31);
        int e = eidx[slot];
        float4 v = *(const float4*)&ea[(size_t)e * DD + j * 4];
        uint2 p; p.x = bc2(v.x, v.y); p.y = bc2(v.z, v.w);
        *(uint2*)&eb[u * 4] = p;
    }
}

// ---- fused MFMA MLP (both ROWS=32, 4 waves) — r9 structure + deep load pipelining ----
// r10 lessons: ROWS=64/8-wave regressed (b32 H' writes -> 7.9M bank conflicts) and the
// L2 weight BANDWIDTH theory was wrong (10 of 34.5 TB/s). r11 theory: VGPR_Count=64
// (exact 8-wave squeeze) means the allocator keeps ~2 weight frags in flight -> the
// unrolled K-loops serialize on ~300cy L2 latency. Fix: explicit 2-deep double-buffer
// of weight fragments (wb/wb2) forces the liveness, and the node agg loop gets
// index-based addressing + unroll-4 (was a serial er+=DD chain, ~de x 300cy).
// Everything else identical to r9 (CSR-sorted bf16 edge state, LDS t_old readback,
// lane-consecutive coalesced bf16 stores, fused contiguous-span mean-agg).
template <int K1, int ROWS_TOTAL, bool EDGE>
__global__ __launch_bounds__(256, 4)
void mlp_mfma(const unsigned short* __restrict__ xb16,
              const int* __restrict__ erow, const int* __restrict__ ecol,   // CSR-sorted for EDGE
              const unsigned short* __restrict__ eas16,   // bf16 edge state (slot order)
              const int* __restrict__ starts, const int* __restrict__ cnt,
              const float* __restrict__ cinv,             // NODE only
              const int* __restrict__ eidx,               // EDGE final layer: slot -> orig edge
              float* __restrict__ target,                 // NODE: fp32 x state; EDGE: final f32 out or null
              unsigned short* __restrict__ shadow,        // NODE: xb16 ; EDGE: eas16_s
              const unsigned short* __restrict__ W1p, const unsigned short* __restrict__ W2p,
              const float* __restrict__ b1, const float* __restrict__ g1, const float* __restrict__ bt1,
              const float* __restrict__ b2, const float* __restrict__ g2, const float* __restrict__ bt2)
{
    constexpr int S1 = K1 / 32;
    constexpr int ROWS = 32;
    __shared__ union {
        unsigned short a1[ROWS * K1];     // gather tile (bf16, XOR-swizzled groups of 8)
        unsigned short h[ROWS * 256];     // stage-1 activations, nibble-swapped col layout
    } sm;
    __shared__ float red1[ROWS][8];
    __shared__ float red2[ROWS][8];

    const int tid  = threadIdx.x;
    const int lane = tid & 63;
    const int w    = tid >> 6;
    const int q    = lane >> 4;
    const int c15  = lane & 15;
    const int r0   = blockIdx.x * ROWS;

    const int qn = w & 3;      // stage-1 n-quad
    const int np = w & 3;      // stage-2 n-pair

    // ---------------- gather -> a1: thread owns row r=tid>>3, col-group g=tid&7 ----------------
    {
        const int r = tid >> 3;
        const int g = tid & 7;
        const int row_g = r0 + r;
        const bool ok = (ROWS_TOTAL % ROWS == 0) || (row_g < ROWS_TOTAL);
        const int rg = ok ? row_g : 0;
        if constexpr (EDGE) {
            const unsigned short* baseA = &xb16[(size_t)erow[rg] * DD];
            const unsigned short* baseB = &xb16[(size_t)ecol[rg] * DD];
            const unsigned short* baseC = &eas16[(size_t)rg * DD];
            #pragma unroll
            for (int it = 0; it < 6; ++it) {
                const int gg = g + 8 * it;
                const int p = gg << 3;                  // region uniform per it
                const unsigned short* src = (p < 128) ? (baseA + p)
                                          : (p < 256) ? (baseB + (p - 128))
                                                      : (baseC + (p - 256));
                uint4 v = *(const uint4*)src;
                *(uint4*)&sm.a1[r * K1 + ((gg ^ (r & 7)) << 3)] = v;
            }
        } else {
            // cols 0..127: bf16 x row
            const unsigned short* baseA = &xb16[(size_t)rg * DD];
            #pragma unroll
            for (int it = 0; it < 2; ++it) {
                const int gg = g + 8 * it;
                uint4 v = *(const uint4*)(baseA + (gg << 3));
                *(uint4*)&sm.a1[r * K1 + ((gg ^ (r & 7)) << 3)] = v;
            }
            // cols 128..255: fused CSR mean over CONTIGUOUS bf16 edge-state span.
            // Index-based addressing + unroll-4: 8 independent loads per group
            // (the r9 serial er+=DD chain cost ~de x 300cy of pure L2 latency).
            const int st = starts[rg];
            const int de = cnt[rg];
            const float ci = cinv[rg];
            float4 sa0 = {0.f,0.f,0.f,0.f}, sa1 = sa0, sb0 = sa0, sb1 = sa0;
            const unsigned short* erb = &eas16[(size_t)st * DD + (g << 3)];
            #pragma unroll 4
            for (int i = 0; i < de; ++i) {
                const unsigned short* er = erb + (size_t)i * DD;
                uint4 a = *(const uint4*)er;          // cols 8g..8g+7
                uint4 b = *(const uint4*)(er + 64);   // cols 64+8g..64+8g+7
                sa0.x += bfl(a.x); sa0.y += bfh(a.x); sa0.z += bfl(a.y); sa0.w += bfh(a.y);
                sa1.x += bfl(a.z); sa1.y += bfh(a.z); sa1.z += bfl(a.w); sa1.w += bfh(a.w);
                sb0.x += bfl(b.x); sb0.y += bfh(b.x); sb0.z += bfl(b.y); sb0.w += bfh(b.y);
                sb1.x += bfl(b.z); sb1.y += bfh(b.z); sb1.z += bfl(b.w); sb1.w += bfh(b.w);
            }
            uint4 v;
            v.x = bc2(sa0.x * ci, sa0.y * ci); v.y = bc2(sa0.z * ci, sa0.w * ci);
            v.z = bc2(sa1.x * ci, sa1.y * ci); v.w = bc2(sa1.z * ci, sa1.w * ci);
            const int gg2 = g + 16;           // agg cols 8g..8g+7 -> virtual cols 128+8g
            *(uint4*)&sm.a1[r * K1 + ((gg2 ^ (r & 7)) << 3)] = v;
            v.x = bc2(sb0.x * ci, sb0.y * ci); v.y = bc2(sb0.z * ci, sb0.w * ci);
            v.z = bc2(sb1.x * ci, sb1.y * ci); v.w = bc2(sb1.z * ci, sb1.w * ci);
            const int gg3 = g + 24;           // agg cols 64+8g.. -> virtual cols 192+8g
            *(uint4*)&sm.a1[r * K1 + ((gg3 ^ (r & 7)) << 3)] = v;
        }
    }
    __syncthreads();

    // hoisted stage-2 bias/gain loads: latency hides under stage-1 MFMA (6 VGPR)
    float b2c[2], g2c[2], t2c[2];
    #pragma unroll
    for (int jn = 0; jn < 2; ++jn) {
        int col = (((np << 1) + jn) << 4) + c15;
        b2c[jn] = b2[col]; g2c[jn] = g2[col]; t2c[jn] = bt2[col];
    }

    // ---------------- stage 1 MFMA: n-quad qn x m-tiles 0,1; weights 2-deep pipelined ----------------
    floatx4 acc[2][4];
    #pragma unroll
    for (int mt = 0; mt < 2; ++mt)
        #pragma unroll
        for (int ntl = 0; ntl < 4; ++ntl)
            acc[mt][ntl] = (floatx4){0.f, 0.f, 0.f, 0.f};

    short8 wb[2][4];     // 32 VGPR of forced weight liveness (defeats the 64-VGPR squeeze)
    #pragma unroll
    for (int ntl = 0; ntl < 4; ++ntl)
        wb[0][ntl] = *(const short8*)&W1p[(((((qn << 2) + ntl) * S1 + 0) << 6) + lane) << 3];
    #pragma unroll
    for (int ntl = 0; ntl < 4; ++ntl)
        wb[1][ntl] = *(const short8*)&W1p[(((((qn << 2) + ntl) * S1 + 1) << 6) + lane) << 3];

    __builtin_amdgcn_s_setprio(1);
    #pragma unroll
    for (int s = 0; s < S1; ++s) {
        short8 af[2];
        #pragma unroll
        for (int mt = 0; mt < 2; ++mt) {
            int row  = (mt << 4) + c15;
            int kgrp = ((s << 2) + q) ^ (row & 7);
            af[mt] = *(const short8*)&sm.a1[row * K1 + (kgrp << 3)];
        }
        #pragma unroll
        for (int ntl = 0; ntl < 4; ++ntl) {
            #pragma unroll
            for (int mt = 0; mt < 2; ++mt)
                acc[mt][ntl] = __builtin_amdgcn_mfma_f32_16x16x32_bf16(af[mt], wb[s & 1][ntl], acc[mt][ntl], 0, 0, 0);
        }
        if (s + 2 < S1) {   // reload the just-consumed buffer with s+2 (compile-time per unrolled iter)
            #pragma unroll
            for (int ntl = 0; ntl < 4; ++ntl)
                wb[s & 1][ntl] = *(const short8*)&W1p[(((((qn << 2) + ntl) * S1 + (s + 2)) << 6) + lane) << 3];
        }
    }
    __builtin_amdgcn_s_setprio(0);

    // EDGE residual t_old: read own-row bf16 state back from the gather tile in LDS
    // (virtual cols 256..383; a1 intact until sm.h writes after the red1 barrier)
    float tpre[2][4][2];
    if constexpr (EDGE) {
        #pragma unroll
        for (int jm = 0; jm < 2; ++jm)
            #pragma unroll
            for (int r = 0; r < 4; ++r) {
                int row = (jm << 4) + (q << 2) + r;
                #pragma unroll
                for (int jn = 0; jn < 2; ++jn) {
                    int col = (((np << 1) + jn) << 4) + c15;
                    int vc = 256 + col;
                    int addr = row * K1 + ((((vc >> 3) ^ (row & 7)) << 3) | (vc & 7));
                    tpre[jm][r][jn] = __uint_as_float((unsigned)sm.a1[addr] << 16);
                }
            }
    }

    // bias + in-register LN1 partial stats
    float b1c[4], g1c[4], t1c[4];
    #pragma unroll
    for (int ntl = 0; ntl < 4; ++ntl) {
        int col = (((qn << 2) + ntl) << 4) + c15;
        b1c[ntl] = b1[col]; g1c[ntl] = g1[col]; t1c[ntl] = bt1[col];
    }
    #pragma unroll
    for (int mt = 0; mt < 2; ++mt)
        #pragma unroll
        for (int r = 0; r < 4; ++r) {
            float p = 0.f, sq = 0.f;
            #pragma unroll
            for (int ntl = 0; ntl < 4; ++ntl) {
                float v = acc[mt][ntl][r] + b1c[ntl];
                acc[mt][ntl][r] = v;
                p += v; sq += v * v;
            }
            p += __shfl_xor(p, 1);  sq += __shfl_xor(sq, 1);
            p += __shfl_xor(p, 2);  sq += __shfl_xor(sq, 2);
            p += __shfl_xor(p, 4);  sq += __shfl_xor(sq, 4);
            p += __shfl_xor(p, 8);  sq += __shfl_xor(sq, 8);
            if (c15 == 0) {
                int row = (mt << 4) + (q << 2) + r;
                red1[row][(qn << 1) + 0] = p;
                red1[row][(qn << 1) + 1] = sq;
            }
        }
    __syncthreads();   // red1 visible; all waves done with a1 (incl. t_old reads) -> h writes safe

    // ---- apply LN1 + GELU in reg, write H' once as b64 (nibble-swapped cols) ----
    #pragma unroll
    for (int mt = 0; mt < 2; ++mt)
        #pragma unroll
        for (int r = 0; r < 4; ++r) {
            int row = (mt << 4) + (q << 2) + r;
            const float4 p0 = *(const float4*)&red1[row][0];
            const float4 p1 = *(const float4*)&red1[row][4];
            float p  = p0.x + p0.z + p1.x + p1.z;
            float sq = p0.y + p0.w + p1.y + p1.w;
            float mu = p * (1.0f / 256.0f);
            float rs = rsqrtf(sq * (1.0f / 256.0f) - mu * mu + LN_EPS);
            float y0 = gelu_fast((acc[mt][0][r] - mu) * rs * g1c[0] + t1c[0]);
            float y1 = gelu_fast((acc[mt][1][r] - mu) * rs * g1c[1] + t1c[1]);
            float y2 = gelu_fast((acc[mt][2][r] - mu) * rs * g1c[2] + t1c[2]);
            float y3 = gelu_fast((acc[mt][3][r] - mu) * rs * g1c[3] + t1c[3]);
            uint2 hp;
            hp.x = bc2(y0, y1);
            hp.y = bc2(y2, y3);
            int gg = (c15 << 1) + (qn >> 1);
            int addr = row * 256 + (((gg ^ (row & 7)) << 3) | ((qn & 1) << 2));
            *(uint2*)&sm.h[addr] = hp;
        }
    __syncthreads();

    // ---------------- stage 2: n-pair np x m-tiles 0,1; weights 2-deep pipelined ----------------
    floatx4 acc2[2][2];
    #pragma unroll
    for (int jm = 0; jm < 2; ++jm)
        #pragma unroll
        for (int jn = 0; jn < 2; ++jn)
            acc2[jm][jn] = (floatx4){0.f, 0.f, 0.f, 0.f};

    short8 wb2[2][2];
    #pragma unroll
    for (int jn = 0; jn < 2; ++jn)
        wb2[0][jn] = *(const short8*)&W2p[(((((np << 1) + jn) << 3) + 0) << 6 << 3) + (lane << 3)];
    #pragma unroll
    for (int jn = 0; jn < 2; ++jn)
        wb2[1][jn] = *(const short8*)&W2p[((((((np << 1) + jn) << 3) + 1) << 6) + lane) << 3];

    __builtin_amdgcn_s_setprio(1);
    #pragma unroll
    for (int s = 0; s < 8; ++s) {
        short8 a2[2];
        #pragma unroll
        for (int jm = 0; jm < 2; ++jm) {
            int mrow = (jm << 4) + c15;
            int kgrp = ((s << 2) + q) ^ (mrow & 7);
            a2[jm] = *(const short8*)&sm.h[mrow * 256 + (kgrp << 3)];
        }
        #pragma unroll
        for (int jn = 0; jn < 2; ++jn) {
            #pragma unroll
            for (int jm = 0; jm < 2; ++jm)
                acc2[jm][jn] = __builtin_amdgcn_mfma_f32_16x16x32_bf16(a2[jm], wb2[s & 1][jn], acc2[jm][jn], 0, 0, 0);
        }
        if (s + 2 < 8) {
            #pragma unroll
            for (int jn = 0; jn < 2; ++jn)
                wb2[s & 1][jn] = *(const short8*)&W2p[((((((np << 1) + jn) << 3) + (s + 2)) << 6) + lane) << 3];
        }
    }
    __builtin_amdgcn_s_setprio(0);

    // NODE residual t_old: prefetch fp32 x state; latency hides under red2 shuffles+barrier
    if constexpr (!EDGE) {
        #pragma unroll
        for (int jm = 0; jm < 2; ++jm)
            #pragma unroll
            for (int r = 0; r < 4; ++r) {
                int row = (jm << 4) + (q << 2) + r;
                int rowg = r0 + row;
                const bool okk = (ROWS_TOTAL % ROWS == 0) || (rowg < ROWS_TOTAL);
                const int rgs = okk ? rowg : 0;
                #pragma unroll
                for (int jn = 0; jn < 2; ++jn) {
                    int col = (((np << 1) + jn) << 4) + c15;
                    tpre[jm][r][jn] = target[(size_t)rgs * DD + col];
                }
            }
    }

    #pragma unroll
    for (int jm = 0; jm < 2; ++jm)
        #pragma unroll
        for (int r = 0; r < 4; ++r) {
            float p = 0.f, sq = 0.f;
            #pragma unroll
            for (int jn = 0; jn < 2; ++jn) {
                float v = acc2[jm][jn][r] + b2c[jn];
                acc2[jm][jn][r] = v;
                p += v; sq += v * v;
            }
            p += __shfl_xor(p, 1);  sq += __shfl_xor(sq, 1);
            p += __shfl_xor(p, 2);  sq += __shfl_xor(sq, 2);
            p += __shfl_xor(p, 4);  sq += __shfl_xor(sq, 4);
            p += __shfl_xor(p, 8);  sq += __shfl_xor(sq, 8);
            if (c15 == 0) {
                int row = (jm << 4) + (q << 2) + r;
                red2[row][(np << 1) + 0] = p;
                red2[row][(np << 1) + 1] = sq;
            }
        }
    __syncthreads();   // red2 visible; all stage-2 h reads done -> h region reusable

    // ---------------- epilogue: LN2 + residual ----------------
    #pragma unroll
    for (int jm = 0; jm < 2; ++jm)
        #pragma unroll
        for (int r = 0; r < 4; ++r) {
            int row = (jm << 4) + (q << 2) + r;
            const float4 pp0 = *(const float4*)&red2[row][0];
            const float4 pp1 = *(const float4*)&red2[row][4];
            float p  = pp0.x + pp0.z + pp1.x + pp1.z;
            float sq = pp0.y + pp0.w + pp1.y + pp1.w;
            float mu = p * (1.0f / 128.0f);
            float rs = rsqrtf(sq * (1.0f / 128.0f) - mu * mu + LN_EPS);
            int rowg = r0 + row;
            const bool okk = (ROWS_TOTAL % ROWS == 0) || (rowg < ROWS_TOTAL);
            #pragma unroll
            for (int jn = 0; jn < 2; ++jn) {
                int col = (((np << 1) + jn) << 4) + c15;
                float o = (acc2[jm][jn][r] - mu) * rs * g2c[jn] + t2c[jn];
                float t = tpre[jm][r][jn] + o;
                if constexpr (EDGE) {
                    // stage bf16 into dead h region (group-XOR swizzle); coalesced store below
                    int oaddr = row * 128 + ((((col >> 3) ^ (row & 7)) << 3) | (col & 7));
                    sm.h[oaddr] = f2bf(t);
                    if (target) {                        // final layer: fp32 out in ORIGINAL order
                        int orig = eidx[rowg];
                        target[(size_t)orig * DD + col] = t;
                    }
                } else {
                    if (okk) {
                        target[(size_t)rowg * DD + col] = t;
                        shadow[(size_t)rowg * DD + col] = f2bf(t);
                    }
                }
            }
        }

    if constexpr (EDGE) {
        __syncthreads();
        // lane-consecutive coalesced store: chunk c = tid + 256k -> 16B at byte c*16;
        // one wave instruction covers 1KB contiguous (r8's version had lanes 64B apart)
        #pragma unroll
        for (int k = 0; k < 2; ++k) {
            int c = tid + (k << 8);
            int row = c >> 4;
            int G = c & 15;
            uint4 v = *(const uint4*)&sm.h[row * 128 + ((G ^ (row & 7)) << 3)];
            *(uint4*)&shadow[(size_t)(r0 + row) * DD + (G << 3)] = v;
        }
    }
}

extern "C" void kernel_launch(void* const* d_in, const int* in_sizes, int n_in,
                              void* d_out, int out_size, void* d_ws, size_t ws_size,
                              hipStream_t stream) {
    const float* x_in  = (const float*)d_in[0];
    const int*   ei    = (const int*)  d_in[1];
    const float* ea_in = (const float*)d_in[2];
    const float* ew1 = (const float*)d_in[3];
    const float* eb1 = (const float*)d_in[4];
    const float* eg1 = (const float*)d_in[5];
    const float* ebt1= (const float*)d_in[6];
    const float* ew2 = (const float*)d_in[7];
    const float* eb2 = (const float*)d_in[8];
    const float* eg2 = (const float*)d_in[9];
    const float* ebt2= (const float*)d_in[10];
    const float* nw1 = (const float*)d_in[11];
    const float* nb1 = (const float*)d_in[12];
    const float* ng1 = (const float*)d_in[13];
    const float* nbt1= (const float*)d_in[14];
    const float* nw2 = (const float*)d_in[15];
    const float* nb2 = (const float*)d_in[16];
    const float* ng2 = (const float*)d_in[17];
    const float* nbt2= (const float*)d_in[18];

    const int* erow = ei;
    const int* ecol = ei + NE;

    float* xbuf  = (float*)d_out;            // [NN, DD] fp32 x residual state (output 0)
    float* eabuf = (float*)d_out + NN * DD;  // [NE, DD] fp32 edge output (written on last layer)

    // workspace layout
    unsigned short* ew1p  = (unsigned short*)d_ws;
    unsigned short* ew2p  = ew1p + N_EW1;
    unsigned short* nw1p  = ew2p + N_EW2;
    unsigned short* nw2p  = nw1p + N_NW1;
    unsigned short* xb16  = nw2p + N_NW2;            // [NN, DD] bf16 shadow of x
    unsigned short* eas16 = xb16 + (size_t)NN * DD;  // [NE, DD] bf16 edge STATE (CSR slot order)
    int*   cnt    = (int*)(eas16 + (size_t)NE * DD);
    int*   starts = cnt + NN;
    int*   cursor = starts + NN;
    int*   eidx   = cursor + NN;                     // slot -> original edge
    int*   erow_s = eidx + NE;                       // CSR-sorted endpoints
    int*   ecol_s = erow_s + NE;
    float* cinv   = (float*)(ecol_s + NE);

    hipMemcpyAsync(xbuf, x_in, (size_t)NN * DD * sizeof(float), hipMemcpyDeviceToDevice, stream);

    // CSR build (+ sorted endpoint arrays)
    hipMemsetAsync(cnt, 0, NN * sizeof(int), stream);
    hist_kernel<<<(NE + 255) / 256, 256, 0, stream>>>(ecol, cnt);
    scan_kernel<<<1, 256, 0, stream>>>(cnt, starts, cursor, cinv);
    fill_kernel<<<(NE + 255) / 256, 256, 0, stream>>>(erow, ecol, cursor, eidx, erow_s, ecol_s);

    // bf16 x shadow + CSR-ordered bf16 edge state (needs eidx -> after fill)
    {
        int ntot = (NN * DD + NE * DD) / 4;
        init_shadow<<<(ntot + 255) / 256, 256, 0, stream>>>(x_in, ea_in, eidx, xb16, eas16);
    }

    // weight packing (stage-2 weights get the k-permutation)
    {
        int ntot = N_EW1 + N_EW2 + N_NW1 + N_NW2;
        pack_all<<<(ntot + 255) / 256, 256, 0, stream>>>(ew1, ew2, nw1, nw2, ew1p);
    }

    for (int i = 0; i < NL; ++i) {
        mlp_mfma<384, NE, true><<<NE / 32, 256, 0, stream>>>(
            xb16, erow_s, ecol_s, eas16, nullptr, nullptr, nullptr, eidx,
            (i == NL - 1) ? eabuf : nullptr, eas16,
            ew1p + (size_t)i * 384 * 256, ew2p + (size_t)i * 256 * 128,
            eb1 + (size_t)i * 256, eg1 + (size_t)i * 256, ebt1 + (size_t)i * 256,
            eb2 + (size_t)i * 128, eg2 + (size_t)i * 128, ebt2 + (size_t)i * 128);
        mlp_mfma<256, NN, false><<<(NN + 31) / 32, 256, 0, stream>>>(
            xb16, nullptr, nullptr, eas16, starts, cnt, cinv, nullptr,
            xbuf, xb16,
            nw1p + (size_t)i * 256 * 256, nw2p + (size_t)i * 256 * 128,
            nb1 + (size_t)i * 256, ng1 + (size_t)i * 256, nbt1 + (size_t)i * 256,
            nb2 + (size_t)i * 128, ng2 + (size_t)i * 128, nbt2 + (size_t)i * 128);
    }
}